// Round 7
// baseline (192.334 us; speedup 1.0000x reference)
//
#include <hip/hip_runtime.h>
#include <hip/hip_bf16.h>

#define BB 64
#define CC 512
#define NPIX 784
#define KK 32
#define NSPL 13
#define PXB 64             // px per block = 4 MFMA tiles = 1 per wave
#define CW_S 520           // cw LDS row stride (shorts): 260 dw == 4 mod 32
#define XS2_S 72           // xs/A_l row stride (shorts): 36 dw == 4 mod 32

typedef __attribute__((ext_vector_type(8))) short short8;
typedef __attribute__((ext_vector_type(4))) float floatx4;
typedef __attribute__((ext_vector_type(4))) unsigned short ushort4v;

// ws layout (float offsets): W_p [13][64][32][512] fp32, wsum_p [13][64][32]
#define OFF_WP 0
#define OFF_WS (NSPL*BB*KK*CC)     // 13,631,488  (~54.6 MB total)

__device__ __forceinline__ unsigned short f2bf(float f) {
    union { float f; unsigned u; } v; v.f = f;
    return (unsigned short)((v.u + 0x7FFFu + ((v.u >> 16) & 1u)) >> 16);
}
__device__ __forceinline__ float bf2f(unsigned short h) {
    union { unsigned u; float f; } v; v.u = ((unsigned)h) << 16; return v.f;
}

// ---------------------------------------------------------------------------
// Fused kernel: per (split, batch) block of 64 px. 832 blocks, 4 waves.
//  Phase 1: wave w owns px-tile w (16 px x 32 k), x-frags direct from global
//           (register double-buffered), softmax fused, A -> LDS [k][px] bf16.
//  Phase 2: W_p[k][c] = sum_px A[k][px] x[c][px] via MFMA; x re-read
//           (L3-hot) into LDS [c][px] bf16, 4 c-chunks of 128; kdim=64 exact.
// ---------------------------------------------------------------------------
__global__ __launch_bounds__(256) void k_fused(const float* __restrict__ x,
                                               const float* __restrict__ cw,
                                               const float* __restrict__ scale,
                                               float* __restrict__ ws)
{
    __shared__ __align__(16) unsigned char u8[KK * CW_S * 2];    // 33280 B: cs / xs
    __shared__ __align__(16) unsigned short A_l[KK * XS2_S];     //  4608 B
    __shared__ float csq_p[8][KK];
    __shared__ float csq_l[KK];
    __shared__ float wred[KK][8];

    unsigned short* cs = (unsigned short*)u8;   // [32][CW_S]   (phase 1)
    unsigned short* xs = (unsigned short*)u8;   // [128][XS2_S] (phase 2, 18432 B)

    const int t     = threadIdx.x;
    const int lane  = t & 63;
    const int w     = t >> 6;
    const int col   = lane & 15;
    const int quad  = lane >> 4;
    const int split = blockIdx.x;
    const int b     = blockIdx.y;
    const int p0    = split * PXB;

    // ---- stage cw -> bf16 LDS ----
#pragma unroll 4
    for (int j = 0; j < 16; ++j) {
        const int qidx = t + j * 256;
        const int row = qidx >> 7, qc = qidx & 127;
        const float4 v = *(const float4*)&cw[row * CC + qc * 4];
        ushort4v p; p.x = f2bf(v.x); p.y = f2bf(v.y); p.z = f2bf(v.z); p.w = f2bf(v.w);
        *(ushort4v*)&cs[row * CW_S + qc * 4] = p;
    }
    __syncthreads();
    // ---- csq ----
    {
        const int k = t & 31, part = t >> 5;
        float s = 0.f;
        for (int i = 0; i < 64; ++i) {
            const float v = bf2f(cs[k * CW_S + part * 64 + i]);
            s += v * v;
        }
        csq_p[part][k] = s;
    }
    __syncthreads();
    if (t < KK) {
        float s = 0.f;
#pragma unroll
        for (int p = 0; p < 8; ++p) s += csq_p[p][t];
        csq_l[t] = s;
    }
    __syncthreads();

    const float s0 = scale[col], s1 = scale[col + 16];
    const float q0 = csq_l[col], q1 = csq_l[col + 16];

    // ================= Phase 1: wave w owns tile w =================
    {
        const int pxg = p0 + w * 16 + col;
        const int px = (pxg < NPIX) ? pxg : (NPIX - 1);   // clamp (split 12 pads)
        const float* xb = x + (size_t)b * CC * NPIX + px;

        floatx4 acc0 = {0.f, 0.f, 0.f, 0.f};
        floatx4 acc1 = {0.f, 0.f, 0.f, 0.f};
        float xsqp = 0.f;
        float va[8], vb[8];

#pragma unroll
        for (int j = 0; j < 8; ++j) va[j] = xb[(size_t)(quad * 8 + j) * NPIX];

#pragma unroll
        for (int kc = 0; kc < 16; kc += 2) {
            {   // prefetch kc+1
                const int cb = (kc + 1) * 32 + quad * 8;
#pragma unroll
                for (int j = 0; j < 8; ++j) vb[j] = xb[(size_t)(cb + j) * NPIX];
            }
            {   // process kc
#pragma unroll
                for (int j = 0; j < 8; ++j) xsqp += va[j] * va[j];
                short8 a;
#pragma unroll
                for (int j = 0; j < 8; ++j) a[j] = (short)f2bf(va[j]);
                const int cb0 = kc * 32 + quad * 8;
                const short8 b0 = *(const short8*)&cs[col * CW_S + cb0];
                const short8 b1 = *(const short8*)&cs[(col + 16) * CW_S + cb0];
                acc0 = __builtin_amdgcn_mfma_f32_16x16x32_bf16(a, b0, acc0, 0, 0, 0);
                acc1 = __builtin_amdgcn_mfma_f32_16x16x32_bf16(a, b1, acc1, 0, 0, 0);
            }
            if (kc + 2 < 16) {   // prefetch kc+2
                const int cb = (kc + 2) * 32 + quad * 8;
#pragma unroll
                for (int j = 0; j < 8; ++j) va[j] = xb[(size_t)(cb + j) * NPIX];
            }
            {   // process kc+1
#pragma unroll
                for (int j = 0; j < 8; ++j) xsqp += vb[j] * vb[j];
                short8 a;
#pragma unroll
                for (int j = 0; j < 8; ++j) a[j] = (short)f2bf(vb[j]);
                const int cb1 = (kc + 1) * 32 + quad * 8;
                const short8 b0 = *(const short8*)&cs[col * CW_S + cb1];
                const short8 b1 = *(const short8*)&cs[(col + 16) * CW_S + cb1];
                acc0 = __builtin_amdgcn_mfma_f32_16x16x32_bf16(a, b0, acc0, 0, 0, 0);
                acc1 = __builtin_amdgcn_mfma_f32_16x16x32_bf16(a, b1, acc1, 0, 0, 0);
            }
        }

        // xsq across quad slices
        xsqp += __shfl_xor(xsqp, 16);
        xsqp += __shfl_xor(xsqp, 32);

        // fused softmax; A_l rows zeroed for pad px (split 12)
#pragma unroll
        for (int r = 0; r < 4; ++r) {
            const int pl = w * 16 + quad * 4 + r;
            const float xq = __shfl(xsqp, quad * 4 + r);
            const float d0 = s0 * (xq + q0 - 2.f * acc0[r]);
            const float d1 = s1 * (xq + q1 - 2.f * acc1[r]);
            float mx = fmaxf(d0, d1);
            mx = fmaxf(mx, __shfl_xor(mx, 1));
            mx = fmaxf(mx, __shfl_xor(mx, 2));
            mx = fmaxf(mx, __shfl_xor(mx, 4));
            mx = fmaxf(mx, __shfl_xor(mx, 8));
            const float e0 = __expf(d0 - mx), e1 = __expf(d1 - mx);
            float sm = e0 + e1;
            sm += __shfl_xor(sm, 1);
            sm += __shfl_xor(sm, 2);
            sm += __shfl_xor(sm, 4);
            sm += __shfl_xor(sm, 8);
            const float inv = 1.f / sm;
            const bool valid = (p0 + pl) < NPIX;
            A_l[col * XS2_S + pl]        = valid ? f2bf(e0 * inv) : (unsigned short)0;
            A_l[(col + 16) * XS2_S + pl] = valid ? f2bf(e1 * inv) : (unsigned short)0;
        }
    }
    __syncthreads();   // A_l complete; cs dead

    // ---- wsum partials from A_l ----
    {
        const int k = t >> 3, part = t & 7;
        float s = 0.f;
#pragma unroll
        for (int i = 0; i < 8; ++i) s += bf2f(A_l[k * XS2_S + part * 8 + i]);
        wred[k][part] = s;
    }
    __syncthreads();
    if (t < KK) {
        float s = 0.f;
#pragma unroll
        for (int p = 0; p < 8; ++p) s += wred[t][p];
        ws[OFF_WS + (size_t)(split * BB + b) * KK + t] = s;
    }

    // ================= Phase 2 =================
    const float* xbase = x + (size_t)b * CC * NPIX + p0;
    float* Wp = ws + OFF_WP;

    for (int cch = 0; cch < 4; ++cch) {
        __syncthreads();
        // stage x chunk [128 c][64 px] -> bf16 (2048 float4 = 8/thread)
#pragma unroll 2
        for (int j = 0; j < 8; ++j) {
            const int q = t + j * 256;
            const int row = q >> 4, pq = q & 15;
            ushort4v p;
            if (p0 + pq * 4 < NPIX) {
                const float4 v = *(const float4*)&xbase[(size_t)(cch * 128 + row) * NPIX + pq * 4];
                p.x = f2bf(v.x); p.y = f2bf(v.y); p.z = f2bf(v.z); p.w = f2bf(v.w);
            } else { p.x = 0; p.y = 0; p.z = 0; p.w = 0; }
            *(ushort4v*)&xs[row * XS2_S + pq * 4] = p;
        }
        __syncthreads();

        floatx4 a00 = {0.f,0.f,0.f,0.f}, a01 = {0.f,0.f,0.f,0.f};
        floatx4 a10 = {0.f,0.f,0.f,0.f}, a11 = {0.f,0.f,0.f,0.f};
#pragma unroll
        for (int ks = 0; ks < 2; ++ks) {
            const int off = ks * 32 + quad * 8;
            const short8 av0 = *(const short8*)&A_l[col * XS2_S + off];
            const short8 av1 = *(const short8*)&A_l[(col + 16) * XS2_S + off];
            const short8 bv0 = *(const short8*)&xs[(w * 32 + col) * XS2_S + off];
            const short8 bv1 = *(const short8*)&xs[(w * 32 + 16 + col) * XS2_S + off];
            a00 = __builtin_amdgcn_mfma_f32_16x16x32_bf16(av0, bv0, a00, 0, 0, 0);
            a10 = __builtin_amdgcn_mfma_f32_16x16x32_bf16(av1, bv0, a10, 0, 0, 0);
            a01 = __builtin_amdgcn_mfma_f32_16x16x32_bf16(av0, bv1, a01, 0, 0, 0);
            a11 = __builtin_amdgcn_mfma_f32_16x16x32_bf16(av1, bv1, a11, 0, 0, 0);
        }

        // write W partials: D row = k (quad*4+r, +16), col = c
        const size_t sb = (size_t)(split * BB + b) * KK;
        const int cb = cch * 128 + w * 32;
#pragma unroll
        for (int r = 0; r < 4; ++r) {
            const int k0 = quad * 4 + r;
            Wp[(sb + k0) * CC + cb + col]           = a00[r];
            Wp[(sb + k0) * CC + cb + 16 + col]      = a01[r];
            Wp[(sb + k0 + 16) * CC + cb + col]      = a10[r];
            Wp[(sb + k0 + 16) * CC + cb + 16 + col] = a11[r];
        }
    }
}

// ---------------------------------------------------------------------------
// k3: out[b][k][c] = sum_s W_p[s][b][k][c] - (sum_s wsum_p[s][b][k]) * cw[k][c]
// ---------------------------------------------------------------------------
__global__ __launch_bounds__(256) void k3(const float* __restrict__ cw,
                                          const float* __restrict__ ws,
                                          float* __restrict__ out)
{
    const int idx = blockIdx.x * 256 + threadIdx.x;   // 262144 float4s
    const int c4 = idx & 127;
    const int k  = (idx >> 7) & 31;
    const int b  = idx >> 12;

    const float* Wp = ws + OFF_WP;
    float4 s = make_float4(0.f, 0.f, 0.f, 0.f);
#pragma unroll
    for (int sp = 0; sp < NSPL; ++sp) {
        const float4 v = *(const float4*)&Wp[((size_t)(sp * BB + b) * KK + k) * CC + c4 * 4];
        s.x += v.x; s.y += v.y; s.z += v.z; s.w += v.w;
    }
    float wsum = 0.f;
#pragma unroll
    for (int sp = 0; sp < NSPL; ++sp) wsum += ws[OFF_WS + (size_t)(sp * BB + b) * KK + k];

    const float4 c4f = *(const float4*)&cw[k * CC + c4 * 4];
    float4 o;
    o.x = s.x - wsum * c4f.x;
    o.y = s.y - wsum * c4f.y;
    o.z = s.z - wsum * c4f.z;
    o.w = s.w - wsum * c4f.w;
    *(float4*)&out[(size_t)idx * 4] = o;
}

extern "C" void kernel_launch(void* const* d_in, const int* in_sizes, int n_in,
                              void* d_out, int out_size, void* d_ws, size_t ws_size,
                              hipStream_t stream) {
    const float* x     = (const float*)d_in[0];   // (64, 512, 28, 28)
    const float* cw    = (const float*)d_in[1];   // (32, 512)
    const float* scale = (const float*)d_in[2];   // (32,)
    float* out = (float*)d_out;                   // (64, 32, 512)
    float* ws  = (float*)d_ws;

    k_fused<<<dim3(NSPL, BB), dim3(256), 0, stream>>>(x, cw, scale, ws);
    k3<<<dim3(BB * KK * CC / 4 / 256), dim3(256), 0, stream>>>(cw, ws, out);
}